// Round 1
// baseline (547.367 us; speedup 1.0000x reference)
//
#include <hip/hip_runtime.h>
#include <hip/hip_bf16.h>

// ---------------------------------------------------------------------------
// TriangleMultiplicativeUpdate (outgoing), B=1 N=512 C=128, fp32 in/out.
// Pipeline: K0 pack weights bf16
//   -> K1a: LN(z) once -> zn_t (bf16) + proj a,g (row strips)
//   -> K1b: read zn_t -> proj b^T (column strips)   [no LN, no fp32 z read]
//   -> K2 batched per-channel GEMM (bf16 MFMA)
//   -> K3 LN + final proj + gate.
// Workspace (268.6 MB):
//   Wbf  : 6*128*128*2 bf16 (ag,ap,g_w,bg,bp,z_w)
//   a_t  : 128*262144*2   a[d][i*512+k]
//   b_tt : 128*262144*2   b^T[d][j*512+k]
//   g_t  : 128*262144*2   g[d][pos]
//   x_t  : 128*262144*2   x[d][i*512+j]  -- ALIASED with zn_t[pos][128]
//          (zn_t dead after K1b, x_t born in K2: no temporal overlap)
// ---------------------------------------------------------------------------

typedef __attribute__((ext_vector_type(8))) short  bfrag;   // 8 bf16 (4 VGPRs)
typedef __attribute__((ext_vector_type(4))) float  f4acc;   // MFMA 16x16 C/D

static __device__ __forceinline__ unsigned short f2bf(float f) {
    union { float f; unsigned u; } v; v.f = f;
    unsigned r = v.u + 0x7FFFu + ((v.u >> 16) & 1u);   // round-to-nearest-even
    return (unsigned short)(r >> 16);
}
static __device__ __forceinline__ float bf2f(unsigned short h) {
    union { unsigned u; float f; } v; v.u = ((unsigned)h) << 16;
    return v.f;
}
static __device__ __forceinline__ float sigmoidf_(float x) {
    return 1.0f / (1.0f + __expf(-x));
}

// ---------------------------------------------------------------------------
// K0: weights fp32 -> bf16 row-major [out][in]: 0=ag 1=ap 2=g_w 3=bg 4=bp 5=z_w
// ---------------------------------------------------------------------------
__global__ __launch_bounds__(256) void k0_pack(
    const float* __restrict__ w0, const float* __restrict__ w1,
    const float* __restrict__ w2, const float* __restrict__ w3,
    const float* __restrict__ w4, const float* __restrict__ w5,
    unsigned short* __restrict__ Wbf)
{
    int idx = blockIdx.x * 256 + threadIdx.x;       // 6*16384 total
    int m = idx >> 14, r = idx & 16383;
    const float* src = (m == 0) ? w0 : (m == 1) ? w1 : (m == 2) ? w2
                     : (m == 3) ? w3 : (m == 4) ? w4 : w5;
    Wbf[idx] = f2bf(src[r]);
}

// ---------------------------------------------------------------------------
// Shared projection phase: zn LDS tile [64 pos][128 ch] (pitch 136) ->
// NMAT 128x128 projections via 16x16x32 bf16 MFMA, gated epilogue, and
// transposed [d][pos] stores staged through wave-private LDS.
// MFMA fragment mappings (gfx950, HW-verified):
//   A: lane holds A[m=lane&15][k=(lane>>4)*8 + j]
//   B: lane holds B[k=(lane>>4)*8 + j][n=lane&15]
//   C/D: col=lane&15, row=(lane>>4)*4 + reg
// ---------------------------------------------------------------------------
template <int NMAT, bool HAS_G>
static __device__ __forceinline__ void proj_phase(
    const unsigned short* zn, unsigned short (*stg_a)[16 * 72],
    unsigned short (*stg_g)[16 * 72], const float* mask_s,
    const unsigned short* __restrict__ Wbf,
    const float* __restrict__ bias0, const float* __restrict__ bias1,
    const float* __restrict__ bias2,
    unsigned short* __restrict__ out_ab, size_t ab_base,
    unsigned short* __restrict__ out_g, size_t g_base, int t)
{
    const int w = t >> 6, l = t & 63, col = l & 15, q = l >> 4;

    for (int dt = w; dt < 8; dt += 4) {
        f4acc acc[4][NMAT];
#pragma unroll
        for (int mt = 0; mt < 4; ++mt)
#pragma unroll
            for (int m = 0; m < NMAT; ++m)
#pragma unroll
                for (int r = 0; r < 4; ++r) acc[mt][m][r] = 0.0f;

#pragma unroll
        for (int ks = 0; ks < 4; ++ks) {
            bfrag bf[NMAT];
#pragma unroll
            for (int m = 0; m < NMAT; ++m)
                bf[m] = *(const bfrag*)(Wbf + ((m * 128 + dt * 16 + col) * 128
                                               + ks * 32 + q * 8));
#pragma unroll
            for (int mt = 0; mt < 4; ++mt) {
                bfrag af = *(const bfrag*)&zn[(mt * 16 + col) * 136 + ks * 32 + q * 8];
#pragma unroll
                for (int m = 0; m < NMAT; ++m)
                    acc[mt][m] = __builtin_amdgcn_mfma_f32_16x16x32_bf16(
                        af, bf[m], acc[mt][m], 0, 0, 0);
            }
        }

        int d = dt * 16 + col;
        float ba = bias0[d], bb = bias1[d];
        float bg = HAS_G ? bias2[d] : 0.0f;
#pragma unroll
        for (int mt = 0; mt < 4; ++mt) {
            unsigned short pa[4], pg[4];
#pragma unroll
            for (int r = 0; r < 4; ++r) {
                int pos = mt * 16 + q * 4 + r;
                float gate = sigmoidf_(acc[mt][0][r] + ba);
                pa[r] = f2bf(mask_s[pos] * gate * (acc[mt][1][r] + bb));
                if (HAS_G) pg[r] = f2bf(sigmoidf_(acc[mt][NMAT - 1][r] + bg));
            }
            *(uint2*)&stg_a[w][col * 72 + mt * 16 + q * 4] = *(const uint2*)pa;
            if (HAS_G)
                *(uint2*)&stg_g[w][col * 72 + mt * 16 + q * 4] = *(const uint2*)pg;
        }

        // wave-private transpose store: rows of [d][...], 128B runs
        int dl = l >> 3, seg = l & 7;
#pragma unroll
        for (int it = 0; it < 2; ++it) {
            int dd = it * 8 + dl;
            float4 va = *(const float4*)&stg_a[w][dd * 72 + seg * 8];
            *(float4*)(out_ab + (size_t)(dt * 16 + dd) * 262144 + ab_base + seg * 8) = va;
            if (HAS_G) {
                float4 vg = *(const float4*)&stg_g[w][dd * 72 + seg * 8];
                *(float4*)(out_g + (size_t)(dt * 16 + dd) * 262144 + g_base + seg * 8) = vg;
            }
        }
    }
}

// ---------------------------------------------------------------------------
// K1a: row strips of 64 positions. LN in registers (4 thr/pos, 2 shuffles),
// write zn_t (bf16) coalesced, then proj {ag, ap, g}.
// ---------------------------------------------------------------------------
__global__ __launch_bounds__(256) void k1a_kern(
    const float* __restrict__ z, const float* __restrict__ mask,
    const float* __restrict__ lnw, const float* __restrict__ lnb,
    const unsigned short* __restrict__ Wbf,
    const float* __restrict__ ag_b, const float* __restrict__ ap_b,
    const float* __restrict__ g_b,
    unsigned short* __restrict__ a_t, unsigned short* __restrict__ g_t,
    unsigned short* __restrict__ zn_t)
{
    __shared__ unsigned short zn[64 * 136];
    __shared__ unsigned short stg_a[4][16 * 72];
    __shared__ unsigned short stg_g[4][16 * 72];
    __shared__ float mask_s[64];

    const int t = threadIdx.x;
    const int p0 = blockIdx.x << 6;

    if (t < 64) mask_s[t] = mask[p0 + t];

    {   // ---- LayerNorm: 4 threads per position, 32 channels each ----
        int pos = t >> 2, sub = t & 3;
        const float4* zp = (const float4*)z + (size_t)(p0 + pos) * 32 + sub * 8;
        float4 v[8];
        float s = 0.0f, sq = 0.0f;
#pragma unroll
        for (int i = 0; i < 8; ++i) {
            v[i] = zp[i];
            s  += v[i].x + v[i].y + v[i].z + v[i].w;
            sq += v[i].x*v[i].x + v[i].y*v[i].y + v[i].z*v[i].z + v[i].w*v[i].w;
        }
        s += __shfl_xor(s, 1); sq += __shfl_xor(sq, 1);
        s += __shfl_xor(s, 2); sq += __shfl_xor(sq, 2);
        float mean = s * 0.0078125f;
        float var  = sq * 0.0078125f - mean * mean;
        float rstd = rsqrtf(var + 1e-5f);
#pragma unroll
        for (int i = 0; i < 8; ++i) {
            int ch = sub * 32 + i * 4;
            float4 wv = *(const float4*)(lnw + ch);
            float4 bv = *(const float4*)(lnb + ch);
            unsigned short h0 = f2bf((v[i].x - mean) * rstd * wv.x + bv.x);
            unsigned short h1 = f2bf((v[i].y - mean) * rstd * wv.y + bv.y);
            unsigned short h2 = f2bf((v[i].z - mean) * rstd * wv.z + bv.z);
            unsigned short h3 = f2bf((v[i].w - mean) * rstd * wv.w + bv.w);
            uint2 pk;
            pk.x = (unsigned)h0 | ((unsigned)h1 << 16);
            pk.y = (unsigned)h2 | ((unsigned)h3 << 16);
            *(uint2*)&zn[pos * 136 + ch] = pk;
        }
    }
    __syncthreads();

    // ---- coalesced zn_t store from LDS (16B/lane) ----
#pragma unroll
    for (int it = 0; it < 4; ++it) {
        int e = it * 256 + t;
        float4 vv = *(const float4*)&zn[(e >> 4) * 136 + (e & 15) * 8];
        *(float4*)(zn_t + (size_t)p0 * 128 + (size_t)e * 8) = vv;
    }

    proj_phase<3, true>(zn, stg_a, stg_g, mask_s, Wbf, ag_b, ap_b, g_b,
                        a_t, (size_t)p0, g_t, (size_t)p0, t);
}

// ---------------------------------------------------------------------------
// K1b: column strips (col c, rows r0..r0+63). Reads precomputed zn_t — no LN.
// proj {bg, bp} -> b_tt[d][c*512 + r].
// ---------------------------------------------------------------------------
__global__ __launch_bounds__(256) void k1b_kern(
    const unsigned short* __restrict__ zn_t, const float* __restrict__ mask,
    const unsigned short* __restrict__ Wbf,
    const float* __restrict__ bg_b, const float* __restrict__ bp_b,
    unsigned short* __restrict__ b_tt)
{
    __shared__ unsigned short zn[64 * 136];
    __shared__ unsigned short stg_a[4][16 * 72];
    __shared__ float mask_s[64];

    const int t = threadIdx.x;
    const int c  = blockIdx.x & 511;
    const int r0 = (blockIdx.x >> 9) << 6;

    if (t < 64) mask_s[t] = mask[(r0 + t) * 512 + c];

#pragma unroll
    for (int it = 0; it < 4; ++it) {
        int e = it * 256 + t;
        int pl = e >> 4, chunk = e & 15;
        float4 vv = *(const float4*)(zn_t + ((size_t)(r0 + pl) * 512 + c) * 128
                                     + chunk * 8);
        *(float4*)&zn[pl * 136 + chunk * 8] = vv;
    }
    __syncthreads();

    proj_phase<2, false>(zn, stg_a, nullptr, mask_s, Wbf, bg_b, bp_b, nullptr,
                         b_tt, (size_t)c * 512 + r0, nullptr, 0, t);
}

// ---------------------------------------------------------------------------
// K2: per-channel batched GEMM. X_d = A_d * B_d^T, 128x128 tile, BK=32.
// Block swizzle keeps same (d,ti) A-strip on one XCD across its 4 tj uses.
// ---------------------------------------------------------------------------
__global__ __launch_bounds__(256) void k2_gemm(
    const unsigned short* __restrict__ a_t,
    const unsigned short* __restrict__ b_tt,
    unsigned short* __restrict__ x_t)
{
    __shared__ unsigned short As[128 * 40];
    __shared__ unsigned short Bs[128 * 40];

    const int t = threadIdx.x;
    int bx   = blockIdx.x;
    int d4ti = (bx & 7) + ((bx >> 5) << 3);
    int tj   = (bx >> 3) & 3;
    int d    = d4ti >> 2, ti = d4ti & 3;
    int i0 = ti * 128, j0 = tj * 128;
    size_t abase = (size_t)d * 262144 + (size_t)i0 * 512;
    size_t bbase = (size_t)d * 262144 + (size_t)j0 * 512;

    const int w = t >> 6, l = t & 63, col = l & 15, q = l >> 4;
    const int wi = w >> 1, wj = w & 1;

    f4acc acc[4][4];
#pragma unroll
    for (int mt = 0; mt < 4; ++mt)
#pragma unroll
        for (int nt = 0; nt < 4; ++nt)
#pragma unroll
            for (int r = 0; r < 4; ++r) acc[mt][nt][r] = 0.0f;

    for (int k0 = 0; k0 < 512; k0 += 32) {
#pragma unroll
        for (int rep = 0; rep < 2; ++rep) {
            int e = rep * 256 + t;
            int row = e >> 2, ch = e & 3;
            *(float4*)&As[row * 40 + ch * 8] =
                *(const float4*)(a_t + abase + (size_t)row * 512 + k0 + ch * 8);
            *(float4*)&Bs[row * 40 + ch * 8] =
                *(const float4*)(b_tt + bbase + (size_t)row * 512 + k0 + ch * 8);
        }
        __syncthreads();

        bfrag af[4], bf[4];
#pragma unroll
        for (int mt = 0; mt < 4; ++mt)
            af[mt] = *(const bfrag*)&As[(wi * 64 + mt * 16 + col) * 40 + q * 8];
#pragma unroll
        for (int nt = 0; nt < 4; ++nt)
            bf[nt] = *(const bfrag*)&Bs[(wj * 64 + nt * 16 + col) * 40 + q * 8];
#pragma unroll
        for (int mt = 0; mt < 4; ++mt)
#pragma unroll
            for (int nt = 0; nt < 4; ++nt)
                acc[mt][nt] = __builtin_amdgcn_mfma_f32_16x16x32_bf16(
                    af[mt], bf[nt], acc[mt][nt], 0, 0, 0);
        __syncthreads();
    }

    size_t obase = (size_t)d * 262144;
#pragma unroll
    for (int mt = 0; mt < 4; ++mt)
#pragma unroll
        for (int nt = 0; nt < 4; ++nt)
#pragma unroll
            for (int r = 0; r < 4; ++r) {
                int i_l = wi * 64 + mt * 16 + q * 4 + r;
                int j_l = wj * 64 + nt * 16 + col;
                x_t[obase + (size_t)(i0 + i_l) * 512 + j0 + j_l] = f2bf(acc[mt][nt][r]);
            }
}

// ---------------------------------------------------------------------------
// K3: LN over d of x + final projection (z_w) + bias + gate multiply.
// ---------------------------------------------------------------------------
__global__ __launch_bounds__(256) void k3_out(
    const unsigned short* __restrict__ x_t,
    const unsigned short* __restrict__ g_t,
    const unsigned short* __restrict__ Wz,
    const float* __restrict__ z_b,
    const float* __restrict__ lnow, const float* __restrict__ lnob,
    float* __restrict__ out)
{
    __shared__ unsigned short xs[128 * 72];
    __shared__ unsigned short gs[128 * 72];
    __shared__ unsigned short xn[64 * 136];
    __shared__ float low_s[128], lob_s[128];

    const int t = threadIdx.x;
    const int p0 = blockIdx.x << 6;

    if (t < 128) { low_s[t] = lnow[t]; lob_s[t] = lnob[t]; }
#pragma unroll
    for (int rep = 0; rep < 4; ++rep) {
        int e = rep * 256 + t;
        int dd = e >> 3, ch = e & 7;
        *(float4*)&xs[dd * 72 + ch * 8] =
            *(const float4*)(x_t + (size_t)dd * 262144 + p0 + ch * 8);
        *(float4*)&gs[dd * 72 + ch * 8] =
            *(const float4*)(g_t + (size_t)dd * 262144 + p0 + ch * 8);
    }
    __syncthreads();

    {   // LN stats: 4 threads per position, 32 channels each
        int pos = t >> 2, sub = t & 3;
        float vals[32];
        float s = 0.0f, sq = 0.0f;
#pragma unroll
        for (int i = 0; i < 32; ++i) {
            float v = bf2f(xs[(sub * 32 + i) * 72 + pos]);
            vals[i] = v; s += v; sq += v * v;
        }
        s += __shfl_xor(s, 1); sq += __shfl_xor(sq, 1);
        s += __shfl_xor(s, 2); sq += __shfl_xor(sq, 2);
        float mean = s * 0.0078125f;
        float var  = sq * 0.0078125f - mean * mean;
        float rstd = rsqrtf(var + 1e-5f);
#pragma unroll
        for (int i = 0; i < 32; ++i) {
            int dd = sub * 32 + i;
            xn[pos * 136 + dd] = f2bf((vals[i] - mean) * rstd * low_s[dd] + lob_s[dd]);
        }
    }
    __syncthreads();

    const int w = t >> 6, l = t & 63, col = l & 15, q = l >> 4;
    f4acc acc[4][2];
#pragma unroll
    for (int mt = 0; mt < 4; ++mt)
#pragma unroll
        for (int i = 0; i < 2; ++i)
#pragma unroll
            for (int r = 0; r < 4; ++r) acc[mt][i][r] = 0.0f;

#pragma unroll
    for (int ks = 0; ks < 4; ++ks) {
        bfrag b0 = *(const bfrag*)(Wz + ((w * 16 + col) * 128 + ks * 32 + q * 8));
        bfrag b1 = *(const bfrag*)(Wz + (((w + 4) * 16 + col) * 128 + ks * 32 + q * 8));
#pragma unroll
        for (int mt = 0; mt < 4; ++mt) {
            bfrag af = *(const bfrag*)&xn[(mt * 16 + col) * 136 + ks * 32 + q * 8];
            acc[mt][0] = __builtin_amdgcn_mfma_f32_16x16x32_bf16(af, b0, acc[mt][0], 0, 0, 0);
            acc[mt][1] = __builtin_amdgcn_mfma_f32_16x16x32_bf16(af, b1, acc[mt][1], 0, 0, 0);
        }
    }

#pragma unroll
    for (int i = 0; i < 2; ++i) {
        int n = (w + i * 4) * 16 + col;
        float zb = z_b[n];
#pragma unroll
        for (int mt = 0; mt < 4; ++mt)
#pragma unroll
            for (int r = 0; r < 4; ++r) {
                int pos = mt * 16 + q * 4 + r;
                float gv = bf2f(gs[n * 72 + pos]);
                out[(size_t)(p0 + pos) * 128 + n] = (acc[mt][i][r] + zb) * gv;
            }
    }
}

// ---------------------------------------------------------------------------
extern "C" void kernel_launch(void* const* d_in, const int* in_sizes, int n_in,
                              void* d_out, int out_size, void* d_ws, size_t ws_size,
                              hipStream_t stream)
{
    const float* z    = (const float*)d_in[0];
    const float* mask = (const float*)d_in[1];
    const float* lnw  = (const float*)d_in[2];
    const float* lnb  = (const float*)d_in[3];
    const float* ag_w = (const float*)d_in[4];
    const float* ag_b = (const float*)d_in[5];
    const float* ap_w = (const float*)d_in[6];
    const float* ap_b = (const float*)d_in[7];
    const float* bg_w = (const float*)d_in[8];
    const float* bg_b = (const float*)d_in[9];
    const float* bp_w = (const float*)d_in[10];
    const float* bp_b = (const float*)d_in[11];
    const float* lnow = (const float*)d_in[12];
    const float* lnob = (const float*)d_in[13];
    const float* z_w  = (const float*)d_in[14];
    const float* z_b  = (const float*)d_in[15];
    const float* g_w  = (const float*)d_in[16];
    const float* g_b  = (const float*)d_in[17];
    float* out = (float*)d_out;

    char* ws = (char*)d_ws;
    unsigned short* Wbf  = (unsigned short*)ws;                 // 6*16384 bf16
    unsigned short* a_t  = (unsigned short*)(ws + 196608);
    unsigned short* b_tt = a_t  + 33554432;
    unsigned short* g_t  = b_tt + 33554432;
    unsigned short* x_t  = g_t  + 33554432;
    unsigned short* zn_t = x_t;   // alias: zn_t dead after K1b, x_t born in K2

    k0_pack<<<384, 256, 0, stream>>>(ag_w, ap_w, g_w, bg_w, bp_w, z_w, Wbf);
    k1a_kern<<<4096, 256, 0, stream>>>(z, mask, lnw, lnb, Wbf,
                                       ag_b, ap_b, g_b, a_t, g_t, zn_t);
    k1b_kern<<<4096, 256, 0, stream>>>(zn_t, mask, Wbf + 3 * 16384,
                                       bg_b, bp_b, b_tt);
    k2_gemm<<<2048, 256, 0, stream>>>(a_t, b_tt, x_t);
    k3_out<<<4096, 256, 0, stream>>>(x_t, g_t, Wbf + 5 * 16384, z_b, lnow, lnob, out);

    (void)in_sizes; (void)n_in; (void)out_size; (void)ws_size;
}

// Round 2
// 543.216 us; speedup vs baseline: 1.0076x; 1.0076x over previous
//
#include <hip/hip_runtime.h>
#include <hip/hip_bf16.h>

// ---------------------------------------------------------------------------
// TriangleMultiplicativeUpdate (outgoing), B=1 N=512 C=128, fp32 in/out.
// Pipeline: K0 pack weights bf16
//   -> K1ln: LN(z) -> zn_t (bf16)          [lean streaming kernel, high occ]
//   -> K1p : zn_t row strips -> proj a,g   [no LN regs -> high occupancy]
//   -> K1b : zn_t col strips -> proj b^T
//   -> K2 batched per-channel GEMM (bf16 MFMA)
//   -> K3 LN + final proj + gate.
// Workspace (268.6 MB):
//   Wbf  : 6*128*128*2 bf16 (ag,ap,g_w,bg,bp,z_w)
//   a_t  : 128*262144*2   a[d][i*512+k]
//   b_tt : 128*262144*2   b^T[d][j*512+k]
//   g_t  : 128*262144*2   g[d][pos]
//   x_t  : 128*262144*2   x[d][i*512+j]  -- ALIASED with zn_t[pos][128]
//          (zn_t dead after K1b, x_t born in K2: no temporal overlap)
// ---------------------------------------------------------------------------

typedef __attribute__((ext_vector_type(8))) short  bfrag;   // 8 bf16 (4 VGPRs)
typedef __attribute__((ext_vector_type(4))) float  f4acc;   // MFMA 16x16 C/D

static __device__ __forceinline__ unsigned short f2bf(float f) {
    union { float f; unsigned u; } v; v.f = f;
    unsigned r = v.u + 0x7FFFu + ((v.u >> 16) & 1u);   // round-to-nearest-even
    return (unsigned short)(r >> 16);
}
static __device__ __forceinline__ float bf2f(unsigned short h) {
    union { unsigned u; float f; } v; v.u = ((unsigned)h) << 16;
    return v.f;
}
static __device__ __forceinline__ float sigmoidf_(float x) {
    return 1.0f / (1.0f + __expf(-x));
}

// ---------------------------------------------------------------------------
// K0: weights fp32 -> bf16 row-major [out][in]: 0=ag 1=ap 2=g_w 3=bg 4=bp 5=z_w
// ---------------------------------------------------------------------------
__global__ __launch_bounds__(256) void k0_pack(
    const float* __restrict__ w0, const float* __restrict__ w1,
    const float* __restrict__ w2, const float* __restrict__ w3,
    const float* __restrict__ w4, const float* __restrict__ w5,
    unsigned short* __restrict__ Wbf)
{
    int idx = blockIdx.x * 256 + threadIdx.x;       // 6*16384 total
    int m = idx >> 14, r = idx & 16383;
    const float* src = (m == 0) ? w0 : (m == 1) ? w1 : (m == 2) ? w2
                     : (m == 3) ? w3 : (m == 4) ? w4 : w5;
    Wbf[idx] = f2bf(src[r]);
}

// ---------------------------------------------------------------------------
// K1ln: LayerNorm only. 64 positions/block, 4 thr/pos, 2 shuffles.
// z fp32 -> zn bf16 in LDS -> coalesced 16B/lane store to zn_t.
// ~17.4 KB LDS, low VGPR -> near-full occupancy; pure streaming.
// ---------------------------------------------------------------------------
__global__ __launch_bounds__(256) void k1_ln(
    const float* __restrict__ z, const float* __restrict__ lnw,
    const float* __restrict__ lnb, unsigned short* __restrict__ zn_t)
{
    __shared__ unsigned short zn[64 * 136];

    const int t = threadIdx.x;
    const int p0 = blockIdx.x << 6;

    {
        int pos = t >> 2, sub = t & 3;
        const float4* zp = (const float4*)z + (size_t)(p0 + pos) * 32 + sub * 8;
        float4 v[8];
        float s = 0.0f, sq = 0.0f;
#pragma unroll
        for (int i = 0; i < 8; ++i) {
            v[i] = zp[i];
            s  += v[i].x + v[i].y + v[i].z + v[i].w;
            sq += v[i].x*v[i].x + v[i].y*v[i].y + v[i].z*v[i].z + v[i].w*v[i].w;
        }
        s += __shfl_xor(s, 1); sq += __shfl_xor(sq, 1);
        s += __shfl_xor(s, 2); sq += __shfl_xor(sq, 2);
        float mean = s * 0.0078125f;
        float var  = sq * 0.0078125f - mean * mean;
        float rstd = rsqrtf(var + 1e-5f);
#pragma unroll
        for (int i = 0; i < 8; ++i) {
            int ch = sub * 32 + i * 4;
            float4 wv = *(const float4*)(lnw + ch);
            float4 bv = *(const float4*)(lnb + ch);
            unsigned short h0 = f2bf((v[i].x - mean) * rstd * wv.x + bv.x);
            unsigned short h1 = f2bf((v[i].y - mean) * rstd * wv.y + bv.y);
            unsigned short h2 = f2bf((v[i].z - mean) * rstd * wv.z + bv.z);
            unsigned short h3 = f2bf((v[i].w - mean) * rstd * wv.w + bv.w);
            uint2 pk;
            pk.x = (unsigned)h0 | ((unsigned)h1 << 16);
            pk.y = (unsigned)h2 | ((unsigned)h3 << 16);
            *(uint2*)&zn[pos * 136 + ch] = pk;
        }
    }
    __syncthreads();

#pragma unroll
    for (int it = 0; it < 4; ++it) {
        int e = it * 256 + t;
        float4 vv = *(const float4*)&zn[(e >> 4) * 136 + (e & 15) * 8];
        *(float4*)(zn_t + (size_t)p0 * 128 + (size_t)e * 8) = vv;
    }
}

// ---------------------------------------------------------------------------
// Shared projection phase: zn LDS tile [64 pos][128 ch] (pitch 136) ->
// NMAT 128x128 projections via 16x16x32 bf16 MFMA, gated epilogue, and
// transposed [d][pos] stores staged through ONE wave-private LDS buffer
// (a then g time-share it; same-wave DS ops are in-order, no barrier).
// MFMA fragment mappings (gfx950, HW-verified):
//   A: lane holds A[m=lane&15][k=(lane>>4)*8 + j]
//   B: lane holds B[k=(lane>>4)*8 + j][n=lane&15]
//   C/D: col=lane&15, row=(lane>>4)*4 + reg
// ---------------------------------------------------------------------------
template <int NMAT, bool HAS_G>
static __device__ __forceinline__ void proj_phase(
    const unsigned short* zn, unsigned short (*stg)[16 * 72],
    const float* mask_s,
    const unsigned short* __restrict__ Wbf,
    const float* __restrict__ bias0, const float* __restrict__ bias1,
    const float* __restrict__ bias2,
    unsigned short* __restrict__ out_ab, size_t ab_base,
    unsigned short* __restrict__ out_g, size_t g_base, int t)
{
    const int w = t >> 6, l = t & 63, col = l & 15, q = l >> 4;
    const int dl = l >> 3, seg = l & 7;

    for (int dt = w; dt < 8; dt += 4) {
        f4acc acc[4][NMAT];
#pragma unroll
        for (int mt = 0; mt < 4; ++mt)
#pragma unroll
            for (int m = 0; m < NMAT; ++m)
#pragma unroll
                for (int r = 0; r < 4; ++r) acc[mt][m][r] = 0.0f;

#pragma unroll
        for (int ks = 0; ks < 4; ++ks) {
            bfrag bf[NMAT];
#pragma unroll
            for (int m = 0; m < NMAT; ++m)
                bf[m] = *(const bfrag*)(Wbf + ((m * 128 + dt * 16 + col) * 128
                                               + ks * 32 + q * 8));
#pragma unroll
            for (int mt = 0; mt < 4; ++mt) {
                bfrag af = *(const bfrag*)&zn[(mt * 16 + col) * 136 + ks * 32 + q * 8];
#pragma unroll
                for (int m = 0; m < NMAT; ++m)
                    acc[mt][m] = __builtin_amdgcn_mfma_f32_16x16x32_bf16(
                        af, bf[m], acc[mt][m], 0, 0, 0);
            }
        }

        int d = dt * 16 + col;
        float ba = bias0[d], bb = bias1[d];
        float bg = HAS_G ? bias2[d] : 0.0f;
        unsigned short pg[4][4];

        // ---- stage + store a ----
#pragma unroll
        for (int mt = 0; mt < 4; ++mt) {
            unsigned short pa[4];
#pragma unroll
            for (int r = 0; r < 4; ++r) {
                int pos = mt * 16 + q * 4 + r;
                float gate = sigmoidf_(acc[mt][0][r] + ba);
                pa[r] = f2bf(mask_s[pos] * gate * (acc[mt][1][r] + bb));
                if (HAS_G) pg[mt][r] = f2bf(sigmoidf_(acc[mt][NMAT - 1][r] + bg));
            }
            *(uint2*)&stg[w][col * 72 + mt * 16 + q * 4] = *(const uint2*)pa;
        }
#pragma unroll
        for (int it = 0; it < 2; ++it) {
            int dd = it * 8 + dl;
            float4 va = *(const float4*)&stg[w][dd * 72 + seg * 8];
            *(float4*)(out_ab + (size_t)(dt * 16 + dd) * 262144 + ab_base + seg * 8) = va;
        }

        // ---- stage + store g (reuses the same wave-private buffer) ----
        if (HAS_G) {
#pragma unroll
            for (int mt = 0; mt < 4; ++mt)
                *(uint2*)&stg[w][col * 72 + mt * 16 + q * 4] = *(const uint2*)pg[mt];
#pragma unroll
            for (int it = 0; it < 2; ++it) {
                int dd = it * 8 + dl;
                float4 vg = *(const float4*)&stg[w][dd * 72 + seg * 8];
                *(float4*)(out_g + (size_t)(dt * 16 + dd) * 262144 + g_base + seg * 8) = vg;
            }
        }
    }
}

// ---------------------------------------------------------------------------
// K1p: row strips of 64 positions, read zn_t (coalesced), proj {ag, ap, g}.
// ---------------------------------------------------------------------------
__global__ __launch_bounds__(256) void k1p_kern(
    const unsigned short* __restrict__ zn_t, const float* __restrict__ mask,
    const unsigned short* __restrict__ Wbf,
    const float* __restrict__ ag_b, const float* __restrict__ ap_b,
    const float* __restrict__ g_b,
    unsigned short* __restrict__ a_t, unsigned short* __restrict__ g_t)
{
    __shared__ unsigned short zn[64 * 136];
    __shared__ unsigned short stg[4][16 * 72];
    __shared__ float mask_s[64];

    const int t = threadIdx.x;
    const int p0 = blockIdx.x << 6;

    if (t < 64) mask_s[t] = mask[p0 + t];

#pragma unroll
    for (int it = 0; it < 4; ++it) {
        int e = it * 256 + t;
        *(float4*)&zn[(e >> 4) * 136 + (e & 15) * 8] =
            *(const float4*)(zn_t + (size_t)p0 * 128 + (size_t)e * 8);
    }
    __syncthreads();

    proj_phase<3, true>(zn, stg, mask_s, Wbf, ag_b, ap_b, g_b,
                        a_t, (size_t)p0, g_t, (size_t)p0, t);
}

// ---------------------------------------------------------------------------
// K1b: column strips (col c, rows r0..r0+63). proj {bg, bp} -> b_tt[d][c*512+r].
// ---------------------------------------------------------------------------
__global__ __launch_bounds__(256) void k1b_kern(
    const unsigned short* __restrict__ zn_t, const float* __restrict__ mask,
    const unsigned short* __restrict__ Wbf,
    const float* __restrict__ bg_b, const float* __restrict__ bp_b,
    unsigned short* __restrict__ b_tt)
{
    __shared__ unsigned short zn[64 * 136];
    __shared__ unsigned short stg[4][16 * 72];
    __shared__ float mask_s[64];

    const int t = threadIdx.x;
    const int c  = blockIdx.x & 511;
    const int r0 = (blockIdx.x >> 9) << 6;

    if (t < 64) mask_s[t] = mask[(r0 + t) * 512 + c];

#pragma unroll
    for (int it = 0; it < 4; ++it) {
        int e = it * 256 + t;
        int pl = e >> 4, chunk = e & 15;
        float4 vv = *(const float4*)(zn_t + ((size_t)(r0 + pl) * 512 + c) * 128
                                     + chunk * 8);
        *(float4*)&zn[pl * 136 + chunk * 8] = vv;
    }
    __syncthreads();

    proj_phase<2, false>(zn, stg, mask_s, Wbf, bg_b, bp_b, nullptr,
                         b_tt, (size_t)c * 512 + r0, nullptr, 0, t);
}

// ---------------------------------------------------------------------------
// K2: per-channel batched GEMM. X_d = A_d * B_d^T, 128x128 tile, BK=32.
// Block swizzle keeps same (d,ti) A-strip on one XCD across its 4 tj uses.
// ---------------------------------------------------------------------------
__global__ __launch_bounds__(256) void k2_gemm(
    const unsigned short* __restrict__ a_t,
    const unsigned short* __restrict__ b_tt,
    unsigned short* __restrict__ x_t)
{
    __shared__ unsigned short As[128 * 40];
    __shared__ unsigned short Bs[128 * 40];

    const int t = threadIdx.x;
    int bx   = blockIdx.x;
    int d4ti = (bx & 7) + ((bx >> 5) << 3);
    int tj   = (bx >> 3) & 3;
    int d    = d4ti >> 2, ti = d4ti & 3;
    int i0 = ti * 128, j0 = tj * 128;
    size_t abase = (size_t)d * 262144 + (size_t)i0 * 512;
    size_t bbase = (size_t)d * 262144 + (size_t)j0 * 512;

    const int w = t >> 6, l = t & 63, col = l & 15, q = l >> 4;
    const int wi = w >> 1, wj = w & 1;

    f4acc acc[4][4];
#pragma unroll
    for (int mt = 0; mt < 4; ++mt)
#pragma unroll
        for (int nt = 0; nt < 4; ++nt)
#pragma unroll
            for (int r = 0; r < 4; ++r) acc[mt][nt][r] = 0.0f;

    for (int k0 = 0; k0 < 512; k0 += 32) {
#pragma unroll
        for (int rep = 0; rep < 2; ++rep) {
            int e = rep * 256 + t;
            int row = e >> 2, ch = e & 3;
            *(float4*)&As[row * 40 + ch * 8] =
                *(const float4*)(a_t + abase + (size_t)row * 512 + k0 + ch * 8);
            *(float4*)&Bs[row * 40 + ch * 8] =
                *(const float4*)(b_tt + bbase + (size_t)row * 512 + k0 + ch * 8);
        }
        __syncthreads();

        bfrag af[4], bf[4];
#pragma unroll
        for (int mt = 0; mt < 4; ++mt)
            af[mt] = *(const bfrag*)&As[(wi * 64 + mt * 16 + col) * 40 + q * 8];
#pragma unroll
        for (int nt = 0; nt < 4; ++nt)
            bf[nt] = *(const bfrag*)&Bs[(wj * 64 + nt * 16 + col) * 40 + q * 8];
#pragma unroll
        for (int mt = 0; mt < 4; ++mt)
#pragma unroll
            for (int nt = 0; nt < 4; ++nt)
                acc[mt][nt] = __builtin_amdgcn_mfma_f32_16x16x32_bf16(
                    af[mt], bf[nt], acc[mt][nt], 0, 0, 0);
        __syncthreads();
    }

    size_t obase = (size_t)d * 262144;
#pragma unroll
    for (int mt = 0; mt < 4; ++mt)
#pragma unroll
        for (int nt = 0; nt < 4; ++nt)
#pragma unroll
            for (int r = 0; r < 4; ++r) {
                int i_l = wi * 64 + mt * 16 + q * 4 + r;
                int j_l = wj * 64 + nt * 16 + col;
                x_t[obase + (size_t)(i0 + i_l) * 512 + j0 + j_l] = f2bf(acc[mt][nt][r]);
            }
}

// ---------------------------------------------------------------------------
// K3: LN over d of x + final projection (z_w) + bias + gate multiply.
// ---------------------------------------------------------------------------
__global__ __launch_bounds__(256) void k3_out(
    const unsigned short* __restrict__ x_t,
    const unsigned short* __restrict__ g_t,
    const unsigned short* __restrict__ Wz,
    const float* __restrict__ z_b,
    const float* __restrict__ lnow, const float* __restrict__ lnob,
    float* __restrict__ out)
{
    __shared__ unsigned short xs[128 * 72];
    __shared__ unsigned short gs[128 * 72];
    __shared__ unsigned short xn[64 * 136];
    __shared__ float low_s[128], lob_s[128];

    const int t = threadIdx.x;
    const int p0 = blockIdx.x << 6;

    if (t < 128) { low_s[t] = lnow[t]; lob_s[t] = lnob[t]; }
#pragma unroll
    for (int rep = 0; rep < 4; ++rep) {
        int e = rep * 256 + t;
        int dd = e >> 3, ch = e & 7;
        *(float4*)&xs[dd * 72 + ch * 8] =
            *(const float4*)(x_t + (size_t)dd * 262144 + p0 + ch * 8);
        *(float4*)&gs[dd * 72 + ch * 8] =
            *(const float4*)(g_t + (size_t)dd * 262144 + p0 + ch * 8);
    }
    __syncthreads();

    {   // LN stats: 4 threads per position, 32 channels each
        int pos = t >> 2, sub = t & 3;
        float vals[32];
        float s = 0.0f, sq = 0.0f;
#pragma unroll
        for (int i = 0; i < 32; ++i) {
            float v = bf2f(xs[(sub * 32 + i) * 72 + pos]);
            vals[i] = v; s += v; sq += v * v;
        }
        s += __shfl_xor(s, 1); sq += __shfl_xor(sq, 1);
        s += __shfl_xor(s, 2); sq += __shfl_xor(sq, 2);
        float mean = s * 0.0078125f;
        float var  = sq * 0.0078125f - mean * mean;
        float rstd = rsqrtf(var + 1e-5f);
#pragma unroll
        for (int i = 0; i < 32; ++i) {
            int dd = sub * 32 + i;
            xn[pos * 136 + dd] = f2bf((vals[i] - mean) * rstd * low_s[dd] + lob_s[dd]);
        }
    }
    __syncthreads();

    const int w = t >> 6, l = t & 63, col = l & 15, q = l >> 4;
    f4acc acc[4][2];
#pragma unroll
    for (int mt = 0; mt < 4; ++mt)
#pragma unroll
        for (int i = 0; i < 2; ++i)
#pragma unroll
            for (int r = 0; r < 4; ++r) acc[mt][i][r] = 0.0f;

#pragma unroll
    for (int ks = 0; ks < 4; ++ks) {
        bfrag b0 = *(const bfrag*)(Wz + ((w * 16 + col) * 128 + ks * 32 + q * 8));
        bfrag b1 = *(const bfrag*)(Wz + (((w + 4) * 16 + col) * 128 + ks * 32 + q * 8));
#pragma unroll
        for (int mt = 0; mt < 4; ++mt) {
            bfrag af = *(const bfrag*)&xn[(mt * 16 + col) * 136 + ks * 32 + q * 8];
            acc[mt][0] = __builtin_amdgcn_mfma_f32_16x16x32_bf16(af, b0, acc[mt][0], 0, 0, 0);
            acc[mt][1] = __builtin_amdgcn_mfma_f32_16x16x32_bf16(af, b1, acc[mt][1], 0, 0, 0);
        }
    }

#pragma unroll
    for (int i = 0; i < 2; ++i) {
        int n = (w + i * 4) * 16 + col;
        float zb = z_b[n];
#pragma unroll
        for (int mt = 0; mt < 4; ++mt)
#pragma unroll
            for (int r = 0; r < 4; ++r) {
                int pos = mt * 16 + q * 4 + r;
                float gv = bf2f(gs[n * 72 + pos]);
                out[(size_t)(p0 + pos) * 128 + n] = (acc[mt][i][r] + zb) * gv;
            }
    }
}

// ---------------------------------------------------------------------------
extern "C" void kernel_launch(void* const* d_in, const int* in_sizes, int n_in,
                              void* d_out, int out_size, void* d_ws, size_t ws_size,
                              hipStream_t stream)
{
    const float* z    = (const float*)d_in[0];
    const float* mask = (const float*)d_in[1];
    const float* lnw  = (const float*)d_in[2];
    const float* lnb  = (const float*)d_in[3];
    const float* ag_w = (const float*)d_in[4];
    const float* ag_b = (const float*)d_in[5];
    const float* ap_w = (const float*)d_in[6];
    const float* ap_b = (const float*)d_in[7];
    const float* bg_w = (const float*)d_in[8];
    const float* bg_b = (const float*)d_in[9];
    const float* bp_w = (const float*)d_in[10];
    const float* bp_b = (const float*)d_in[11];
    const float* lnow = (const float*)d_in[12];
    const float* lnob = (const float*)d_in[13];
    const float* z_w  = (const float*)d_in[14];
    const float* z_b  = (const float*)d_in[15];
    const float* g_w  = (const float*)d_in[16];
    const float* g_b  = (const float*)d_in[17];
    float* out = (float*)d_out;

    char* ws = (char*)d_ws;
    unsigned short* Wbf  = (unsigned short*)ws;                 // 6*16384 bf16
    unsigned short* a_t  = (unsigned short*)(ws + 196608);
    unsigned short* b_tt = a_t  + 33554432;
    unsigned short* g_t  = b_tt + 33554432;
    unsigned short* x_t  = g_t  + 33554432;
    unsigned short* zn_t = x_t;   // alias: zn_t dead after K1b, x_t born in K2

    k0_pack<<<384, 256, 0, stream>>>(ag_w, ap_w, g_w, bg_w, bp_w, z_w, Wbf);
    k1_ln<<<4096, 256, 0, stream>>>(z, lnw, lnb, zn_t);
    k1p_kern<<<4096, 256, 0, stream>>>(zn_t, mask, Wbf,
                                       ag_b, ap_b, g_b, a_t, g_t);
    k1b_kern<<<4096, 256, 0, stream>>>(zn_t, mask, Wbf + 3 * 16384,
                                       bg_b, bp_b, b_tt);
    k2_gemm<<<2048, 256, 0, stream>>>(a_t, b_tt, x_t);
    k3_out<<<4096, 256, 0, stream>>>(x_t, g_t, Wbf + 5 * 16384, z_b, lnow, lnob, out);

    (void)in_sizes; (void)n_in; (void)out_size; (void)ws_size;
}

// Round 5
// 508.543 us; speedup vs baseline: 1.0763x; 1.0682x over previous
//
#include <hip/hip_runtime.h>
#include <hip/hip_bf16.h>

// ---------------------------------------------------------------------------
// TriangleMultiplicativeUpdate (outgoing), B=1 N=512 C=128, fp32 in/out.
// Pipeline: K0 pack weights bf16
//   -> K1ln: LN(z) -> zn_t (bf16)
//   -> K1p : zn_t row strips -> proj a only      [g moved to K3]
//   -> K1b : zn_t col strips -> proj b^T
//   -> K2 batched per-channel GEMM (bf16 MFMA)
//   -> K3 LN + final proj + g-proj (zn@g_w, same frag indexing) + gate.
// Workspace (268.6 MB):
//   Wbf  : 6*128*128*2 bf16 (ag,ap,g_w,bg,bp,z_w)
//   a_t  : 128*262144*2   a[d][i*512+k]
//   b_tt : 128*262144*2   b^T[d][j*512+k]
//   x_t  : 128*262144*2   x[d][i*512+j]
//   zn_t : 262144*128*2   zn[pos][ch]   (NOT aliased; g_t eliminated)
// ---------------------------------------------------------------------------

typedef __attribute__((ext_vector_type(8))) short  bfrag;   // 8 bf16 (4 VGPRs)
typedef __attribute__((ext_vector_type(4))) float  f4acc;   // MFMA 16x16 C/D

static __device__ __forceinline__ unsigned short f2bf(float f) {
    union { float f; unsigned u; } v; v.f = f;
    unsigned r = v.u + 0x7FFFu + ((v.u >> 16) & 1u);   // round-to-nearest-even
    return (unsigned short)(r >> 16);
}
static __device__ __forceinline__ float bf2f(unsigned short h) {
    union { unsigned u; float f; } v; v.u = ((unsigned)h) << 16;
    return v.f;
}
static __device__ __forceinline__ float sigmoidf_(float x) {
    return 1.0f / (1.0f + __expf(-x));
}

// ---------------------------------------------------------------------------
// K0: weights fp32 -> bf16 row-major [out][in]: 0=ag 1=ap 2=g_w 3=bg 4=bp 5=z_w
// ---------------------------------------------------------------------------
__global__ __launch_bounds__(256) void k0_pack(
    const float* __restrict__ w0, const float* __restrict__ w1,
    const float* __restrict__ w2, const float* __restrict__ w3,
    const float* __restrict__ w4, const float* __restrict__ w5,
    unsigned short* __restrict__ Wbf)
{
    int idx = blockIdx.x * 256 + threadIdx.x;       // 6*16384 total
    int m = idx >> 14, r = idx & 16383;
    const float* src = (m == 0) ? w0 : (m == 1) ? w1 : (m == 2) ? w2
                     : (m == 3) ? w3 : (m == 4) ? w4 : w5;
    Wbf[idx] = f2bf(src[r]);
}

// ---------------------------------------------------------------------------
// K1ln: LayerNorm only. 64 positions/block, 4 thr/pos, 2 shuffles.
// ---------------------------------------------------------------------------
__global__ __launch_bounds__(256) void k1_ln(
    const float* __restrict__ z, const float* __restrict__ lnw,
    const float* __restrict__ lnb, unsigned short* __restrict__ zn_t)
{
    __shared__ unsigned short zn[64 * 136];

    const int t = threadIdx.x;
    const int p0 = blockIdx.x << 6;

    {
        int pos = t >> 2, sub = t & 3;
        const float4* zp = (const float4*)z + (size_t)(p0 + pos) * 32 + sub * 8;
        float4 v[8];
        float s = 0.0f, sq = 0.0f;
#pragma unroll
        for (int i = 0; i < 8; ++i) {
            v[i] = zp[i];
            s  += v[i].x + v[i].y + v[i].z + v[i].w;
            sq += v[i].x*v[i].x + v[i].y*v[i].y + v[i].z*v[i].z + v[i].w*v[i].w;
        }
        s += __shfl_xor(s, 1); sq += __shfl_xor(sq, 1);
        s += __shfl_xor(s, 2); sq += __shfl_xor(sq, 2);
        float mean = s * 0.0078125f;
        float var  = sq * 0.0078125f - mean * mean;
        float rstd = rsqrtf(var + 1e-5f);
#pragma unroll
        for (int i = 0; i < 8; ++i) {
            int ch = sub * 32 + i * 4;
            float4 wv = *(const float4*)(lnw + ch);
            float4 bv = *(const float4*)(lnb + ch);
            unsigned short h0 = f2bf((v[i].x - mean) * rstd * wv.x + bv.x);
            unsigned short h1 = f2bf((v[i].y - mean) * rstd * wv.y + bv.y);
            unsigned short h2 = f2bf((v[i].z - mean) * rstd * wv.z + bv.z);
            unsigned short h3 = f2bf((v[i].w - mean) * rstd * wv.w + bv.w);
            uint2 pk;
            pk.x = (unsigned)h0 | ((unsigned)h1 << 16);
            pk.y = (unsigned)h2 | ((unsigned)h3 << 16);
            *(uint2*)&zn[pos * 136 + ch] = pk;
        }
    }
    __syncthreads();

#pragma unroll
    for (int it = 0; it < 4; ++it) {
        int e = it * 256 + t;
        float4 vv = *(const float4*)&zn[(e >> 4) * 136 + (e & 15) * 8];
        *(float4*)(zn_t + (size_t)p0 * 128 + (size_t)e * 8) = vv;
    }
}

// ---------------------------------------------------------------------------
// Projection phase: zn LDS tile [64 pos][128 ch] (pitch 136) -> 2 128x128
// projections (gate, proj) via 16x16x32 bf16 MFMA, masked-gated epilogue,
// transposed [d][pos] stores staged through a wave-private LDS buffer.
// MFMA fragment mappings (gfx950, HW-verified):
//   A: lane holds A[m=lane&15][k=(lane>>4)*8 + j]
//   B: lane holds B[k=(lane>>4)*8 + j][n=lane&15]
//   C/D: col=lane&15, row=(lane>>4)*4 + reg
// ---------------------------------------------------------------------------
static __device__ __forceinline__ void proj_phase2(
    const unsigned short* zn, unsigned short (*stg)[16 * 72],
    const float* mask_s,
    const unsigned short* __restrict__ Wbf,
    const float* __restrict__ bias0, const float* __restrict__ bias1,
    unsigned short* __restrict__ out_ab, size_t ab_base, int t)
{
    const int w = t >> 6, l = t & 63, col = l & 15, q = l >> 4;
    const int dl = l >> 3, seg = l & 7;

    for (int dt = w; dt < 8; dt += 4) {
        f4acc acc[4][2];
#pragma unroll
        for (int mt = 0; mt < 4; ++mt)
#pragma unroll
            for (int m = 0; m < 2; ++m)
#pragma unroll
                for (int r = 0; r < 4; ++r) acc[mt][m][r] = 0.0f;

#pragma unroll
        for (int ks = 0; ks < 4; ++ks) {
            bfrag bf[2];
#pragma unroll
            for (int m = 0; m < 2; ++m)
                bf[m] = *(const bfrag*)(Wbf + ((m * 128 + dt * 16 + col) * 128
                                               + ks * 32 + q * 8));
#pragma unroll
            for (int mt = 0; mt < 4; ++mt) {
                bfrag af = *(const bfrag*)&zn[(mt * 16 + col) * 136 + ks * 32 + q * 8];
#pragma unroll
                for (int m = 0; m < 2; ++m)
                    acc[mt][m] = __builtin_amdgcn_mfma_f32_16x16x32_bf16(
                        af, bf[m], acc[mt][m], 0, 0, 0);
            }
        }

        int d = dt * 16 + col;
        float ba = bias0[d], bb = bias1[d];

#pragma unroll
        for (int mt = 0; mt < 4; ++mt) {
            unsigned short pa[4];
#pragma unroll
            for (int r = 0; r < 4; ++r) {
                int pos = mt * 16 + q * 4 + r;
                float gate = sigmoidf_(acc[mt][0][r] + ba);
                pa[r] = f2bf(mask_s[pos] * gate * (acc[mt][1][r] + bb));
            }
            *(uint2*)&stg[w][col * 72 + mt * 16 + q * 4] = *(const uint2*)pa;
        }
#pragma unroll
        for (int it = 0; it < 2; ++it) {
            int dd = it * 8 + dl;
            float4 va = *(const float4*)&stg[w][dd * 72 + seg * 8];
            *(float4*)(out_ab + (size_t)(dt * 16 + dd) * 262144 + ab_base + seg * 8) = va;
        }
    }
}

// ---------------------------------------------------------------------------
// K1p: row strips of 64 positions, read zn_t (coalesced), proj {ag, ap} only.
// ---------------------------------------------------------------------------
__global__ __launch_bounds__(256) void k1p_kern(
    const unsigned short* __restrict__ zn_t, const float* __restrict__ mask,
    const unsigned short* __restrict__ Wbf,
    const float* __restrict__ ag_b, const float* __restrict__ ap_b,
    unsigned short* __restrict__ a_t)
{
    __shared__ unsigned short zn[64 * 136];
    __shared__ unsigned short stg[4][16 * 72];
    __shared__ float mask_s[64];

    const int t = threadIdx.x;
    const int p0 = blockIdx.x << 6;

    if (t < 64) mask_s[t] = mask[p0 + t];

#pragma unroll
    for (int it = 0; it < 4; ++it) {
        int e = it * 256 + t;
        *(float4*)&zn[(e >> 4) * 136 + (e & 15) * 8] =
            *(const float4*)(zn_t + (size_t)p0 * 128 + (size_t)e * 8);
    }
    __syncthreads();

    proj_phase2(zn, stg, mask_s, Wbf, ag_b, ap_b, a_t, (size_t)p0, t);
}

// ---------------------------------------------------------------------------
// K1b: column strips (col c, rows r0..r0+63). proj {bg, bp} -> b_tt[d][c*512+r].
// ---------------------------------------------------------------------------
__global__ __launch_bounds__(256) void k1b_kern(
    const unsigned short* __restrict__ zn_t, const float* __restrict__ mask,
    const unsigned short* __restrict__ Wbf,
    const float* __restrict__ bg_b, const float* __restrict__ bp_b,
    unsigned short* __restrict__ b_tt)
{
    __shared__ unsigned short zn[64 * 136];
    __shared__ unsigned short stg[4][16 * 72];
    __shared__ float mask_s[64];

    const int t = threadIdx.x;
    const int c  = blockIdx.x & 511;
    const int r0 = (blockIdx.x >> 9) << 6;

    if (t < 64) mask_s[t] = mask[(r0 + t) * 512 + c];

#pragma unroll
    for (int it = 0; it < 4; ++it) {
        int e = it * 256 + t;
        int pl = e >> 4, chunk = e & 15;
        float4 vv = *(const float4*)(zn_t + ((size_t)(r0 + pl) * 512 + c) * 128
                                     + chunk * 8);
        *(float4*)&zn[pl * 136 + chunk * 8] = vv;
    }
    __syncthreads();

    proj_phase2(zn, stg, mask_s, Wbf, bg_b, bp_b, b_tt, (size_t)c * 512 + r0, t);
}

// ---------------------------------------------------------------------------
// K2: per-channel batched GEMM. X_d = A_d * B_d^T, 128x128 tile, BK=32.
// Block swizzle keeps same (d,ti) A-strip on one XCD across its 4 tj uses.
// ---------------------------------------------------------------------------
__global__ __launch_bounds__(256) void k2_gemm(
    const unsigned short* __restrict__ a_t,
    const unsigned short* __restrict__ b_tt,
    unsigned short* __restrict__ x_t)
{
    __shared__ unsigned short As[128 * 40];
    __shared__ unsigned short Bs[128 * 40];

    const int t = threadIdx.x;
    int bx   = blockIdx.x;
    int d4ti = (bx & 7) + ((bx >> 5) << 3);
    int tj   = (bx >> 3) & 3;
    int d    = d4ti >> 2, ti = d4ti & 3;
    int i0 = ti * 128, j0 = tj * 128;
    size_t abase = (size_t)d * 262144 + (size_t)i0 * 512;
    size_t bbase = (size_t)d * 262144 + (size_t)j0 * 512;

    const int w = t >> 6, l = t & 63, col = l & 15, q = l >> 4;
    const int wi = w >> 1, wj = w & 1;

    f4acc acc[4][4];
#pragma unroll
    for (int mt = 0; mt < 4; ++mt)
#pragma unroll
        for (int nt = 0; nt < 4; ++nt)
#pragma unroll
            for (int r = 0; r < 4; ++r) acc[mt][nt][r] = 0.0f;

    for (int k0 = 0; k0 < 512; k0 += 32) {
#pragma unroll
        for (int rep = 0; rep < 2; ++rep) {
            int e = rep * 256 + t;
            int row = e >> 2, ch = e & 3;
            *(float4*)&As[row * 40 + ch * 8] =
                *(const float4*)(a_t + abase + (size_t)row * 512 + k0 + ch * 8);
            *(float4*)&Bs[row * 40 + ch * 8] =
                *(const float4*)(b_tt + bbase + (size_t)row * 512 + k0 + ch * 8);
        }
        __syncthreads();

        bfrag af[4], bf[4];
#pragma unroll
        for (int mt = 0; mt < 4; ++mt)
            af[mt] = *(const bfrag*)&As[(wi * 64 + mt * 16 + col) * 40 + q * 8];
#pragma unroll
        for (int nt = 0; nt < 4; ++nt)
            bf[nt] = *(const bfrag*)&Bs[(wj * 64 + nt * 16 + col) * 40 + q * 8];
#pragma unroll
        for (int mt = 0; mt < 4; ++mt)
#pragma unroll
            for (int nt = 0; nt < 4; ++nt)
                acc[mt][nt] = __builtin_amdgcn_mfma_f32_16x16x32_bf16(
                    af[mt], bf[nt], acc[mt][nt], 0, 0, 0);
        __syncthreads();
    }

    size_t obase = (size_t)d * 262144;
#pragma unroll
    for (int mt = 0; mt < 4; ++mt)
#pragma unroll
        for (int nt = 0; nt < 4; ++nt)
#pragma unroll
            for (int r = 0; r < 4; ++r) {
                int i_l = wi * 64 + mt * 16 + q * 4 + r;
                int j_l = wj * 64 + nt * 16 + col;
                x_t[obase + (size_t)(i0 + i_l) * 512 + j0 + j_l] = f2bf(acc[mt][nt][r]);
            }
}

// ---------------------------------------------------------------------------
// K3: LN over d of x + final proj (z_w) + g-proj (zn@g_w) + gate multiply.
// The g-proj C/D fragment indexing is identical to the z_w proj, so gating
// happens entirely in registers. LDS: xs (aliased by xn after stats) + zs.
// ---------------------------------------------------------------------------
__global__ __launch_bounds__(256) void k3_out(
    const unsigned short* __restrict__ x_t,
    const unsigned short* __restrict__ zn_t,
    const unsigned short* __restrict__ Wz,
    const unsigned short* __restrict__ Wg,
    const float* __restrict__ z_b, const float* __restrict__ g_b,
    const float* __restrict__ lnow, const float* __restrict__ lnob,
    float* __restrict__ out)
{
    __shared__ unsigned short xs[128 * 72];     // re-used as xn[64*136] after stats
    __shared__ unsigned short zs[64 * 136];
    __shared__ float low_s[128], lob_s[128];

    const int t = threadIdx.x;
    const int p0 = blockIdx.x << 6;

    if (t < 128) { low_s[t] = lnow[t]; lob_s[t] = lnob[t]; }
#pragma unroll
    for (int rep = 0; rep < 4; ++rep) {
        int e = rep * 256 + t;
        int dd = e >> 3, ch = e & 7;
        *(float4*)&xs[dd * 72 + ch * 8] =
            *(const float4*)(x_t + (size_t)dd * 262144 + p0 + ch * 8);
    }
#pragma unroll
    for (int it = 0; it < 4; ++it) {
        int e = it * 256 + t;
        *(float4*)&zs[(e >> 4) * 136 + (e & 15) * 8] =
            *(const float4*)(zn_t + (size_t)p0 * 128 + (size_t)e * 8);
    }
    __syncthreads();

    {   // LN stats: 4 threads per position, 32 channels each; then rewrite
        // normalized values into the xs region with pitch 136 ([pos][d]).
        int pos = t >> 2, sub = t & 3;
        float vals[32];
        float s = 0.0f, sq = 0.0f;
#pragma unroll
        for (int i = 0; i < 32; ++i) {
            float v = bf2f(xs[(sub * 32 + i) * 72 + pos]);
            vals[i] = v; s += v; sq += v * v;
        }
        s += __shfl_xor(s, 1); sq += __shfl_xor(sq, 1);
        s += __shfl_xor(s, 2); sq += __shfl_xor(sq, 2);
        float mean = s * 0.0078125f;
        float var  = sq * 0.0078125f - mean * mean;
        float rstd = rsqrtf(var + 1e-5f);
        __syncthreads();      // all xs reads complete before overwrite
#pragma unroll
        for (int i = 0; i < 32; ++i) {
            int dd = sub * 32 + i;
            xs[pos * 136 + dd] = f2bf((vals[i] - mean) * rstd * low_s[dd] + lob_s[dd]);
        }
    }
    __syncthreads();

    const int w = t >> 6, l = t & 63, col = l & 15, q = l >> 4;
    f4acc acc[4][2], accg[4][2];
#pragma unroll
    for (int mt = 0; mt < 4; ++mt)
#pragma unroll
        for (int i = 0; i < 2; ++i)
#pragma unroll
            for (int r = 0; r < 4; ++r) { acc[mt][i][r] = 0.0f; accg[mt][i][r] = 0.0f; }

#pragma unroll
    for (int ks = 0; ks < 4; ++ks) {
        bfrag b0 = *(const bfrag*)(Wz + ((w * 16 + col) * 128 + ks * 32 + q * 8));
        bfrag b1 = *(const bfrag*)(Wz + (((w + 4) * 16 + col) * 128 + ks * 32 + q * 8));
        bfrag g0 = *(const bfrag*)(Wg + ((w * 16 + col) * 128 + ks * 32 + q * 8));
        bfrag g1 = *(const bfrag*)(Wg + (((w + 4) * 16 + col) * 128 + ks * 32 + q * 8));
#pragma unroll
        for (int mt = 0; mt < 4; ++mt) {
            bfrag ax = *(const bfrag*)&xs[(mt * 16 + col) * 136 + ks * 32 + q * 8];
            bfrag az = *(const bfrag*)&zs[(mt * 16 + col) * 136 + ks * 32 + q * 8];
            acc[mt][0]  = __builtin_amdgcn_mfma_f32_16x16x32_bf16(ax, b0, acc[mt][0], 0, 0, 0);
            acc[mt][1]  = __builtin_amdgcn_mfma_f32_16x16x32_bf16(ax, b1, acc[mt][1], 0, 0, 0);
            accg[mt][0] = __builtin_amdgcn_mfma_f32_16x16x32_bf16(az, g0, accg[mt][0], 0, 0, 0);
            accg[mt][1] = __builtin_amdgcn_mfma_f32_16x16x32_bf16(az, g1, accg[mt][1], 0, 0, 0);
        }
    }

#pragma unroll
    for (int i = 0; i < 2; ++i) {
        int n = (w + i * 4) * 16 + col;
        float zb = z_b[n], gb = g_b[n];
#pragma unroll
        for (int mt = 0; mt < 4; ++mt)
#pragma unroll
            for (int r = 0; r < 4; ++r) {
                int pos = mt * 16 + q * 4 + r;
                float gv = sigmoidf_(accg[mt][i][r] + gb);
                out[(size_t)(p0 + pos) * 128 + n] = (acc[mt][i][r] + zb) * gv;
            }
    }
}

// ---------------------------------------------------------------------------
extern "C" void kernel_launch(void* const* d_in, const int* in_sizes, int n_in,
                              void* d_out, int out_size, void* d_ws, size_t ws_size,
                              hipStream_t stream)
{
    const float* z    = (const float*)d_in[0];
    const float* mask = (const float*)d_in[1];
    const float* lnw  = (const float*)d_in[2];
    const float* lnb  = (const float*)d_in[3];
    const float* ag_w = (const float*)d_in[4];
    const float* ag_b = (const float*)d_in[5];
    const float* ap_w = (const float*)d_in[6];
    const float* ap_b = (const float*)d_in[7];
    const float* bg_w = (const float*)d_in[8];
    const float* bg_b = (const float*)d_in[9];
    const float* bp_w = (const float*)d_in[10];
    const float* bp_b = (const float*)d_in[11];
    const float* lnow = (const float*)d_in[12];
    const float* lnob = (const float*)d_in[13];
    const float* z_w  = (const float*)d_in[14];
    const float* z_b  = (const float*)d_in[15];
    const float* g_w  = (const float*)d_in[16];
    const float* g_b  = (const float*)d_in[17];
    float* out = (float*)d_out;

    char* ws = (char*)d_ws;
    unsigned short* Wbf  = (unsigned short*)ws;                 // 6*16384 bf16
    unsigned short* a_t  = (unsigned short*)(ws + 196608);
    unsigned short* b_tt = a_t  + 33554432;
    unsigned short* x_t  = b_tt + 33554432;
    unsigned short* zn_t = x_t  + 33554432;   // separate: g_t eliminated

    k0_pack<<<384, 256, 0, stream>>>(ag_w, ap_w, g_w, bg_w, bp_w, z_w, Wbf);
    k1_ln<<<4096, 256, 0, stream>>>(z, lnw, lnb, zn_t);
    k1p_kern<<<4096, 256, 0, stream>>>(zn_t, mask, Wbf,
                                       ag_b, ap_b, a_t);
    k1b_kern<<<4096, 256, 0, stream>>>(zn_t, mask, Wbf + 3 * 16384,
                                       bg_b, bp_b, b_tt);
    k2_gemm<<<2048, 256, 0, stream>>>(a_t, b_tt, x_t);
    k3_out<<<4096, 256, 0, stream>>>(x_t, zn_t, Wbf + 5 * 16384, Wbf + 2 * 16384,
                                     z_b, g_b, lnow, lnob, out);

    (void)in_sizes; (void)n_in; (void)out_size; (void)ws_size;
}